// Round 2
// baseline (202.700 us; speedup 1.0000x reference)
//
#include <hip/hip_runtime.h>
#include <hip/hip_bf16.h>

// Problem constants (fixed by reference setup_inputs)
#define M 4096
#define N 8192
#define D 128
#define TI 128
#define TJ 128
#define LDB 136  // padded LDS stride in bf16 elems: 272 B rows -> 16B-aligned, 2-way-bank (free)

typedef __attribute__((ext_vector_type(8))) short short8_t;  // 8 bf16 = 4 VGPRs (MFMA A/B frag)
typedef __attribute__((ext_vector_type(4))) float f32x4;     // MFMA C/D frag

__device__ inline short f2bf(float f) {
    // fp32 -> bf16 round-to-nearest-even (bit trick)
    union { float f; unsigned u; } v; v.f = f;
    unsigned r = v.u + 0x7FFFu + ((v.u >> 16) & 1u);
    return (short)(r >> 16);
}

// Kernel 0: squared row norms of sub_x (-> ws[0:M]) and all_x (-> ws[M:M+N]); zero d_out.
__global__ __launch_bounds__(256) void norms_kernel(const float* __restrict__ sub_x,
                                                    const float* __restrict__ all_x,
                                                    float* __restrict__ ws,
                                                    float* __restrict__ out) {
    int wave = threadIdx.x >> 6;
    int lane = threadIdx.x & 63;
    int row  = blockIdx.x * 4 + wave;   // 12288 rows total = 3072 blocks * 4 waves

    const float* src;
    float* dst;
    if (row < M) { src = sub_x + (size_t)row * D; dst = ws + row; }
    else         { int r = row - M; src = all_x + (size_t)r * D; dst = ws + M + r; }

    float2 v = ((const float2*)src)[lane];          // lane covers elems 2l, 2l+1 (D=128)
    float s = v.x * v.x + v.y * v.y;
    #pragma unroll
    for (int off = 32; off > 0; off >>= 1) s += __shfl_down(s, off, 64);
    if (lane == 0) dst[0] = s;

    if (blockIdx.x == 0 && threadIdx.x == 0) out[0] = 0.0f;
}

// Kernel 1: fused  sum_{i,j} G[i,j] * (sxn[i] + axn[j] - 2*<sx_i, ax_j>)
// One block = 128x128 tile of G. 4 waves; wave w owns output rows [32w, 32w+32).
__global__ __launch_bounds__(256, 3) void graph_loss_kernel(const float* __restrict__ G,
                                                            const float* __restrict__ sub_x,
                                                            const float* __restrict__ all_x,
                                                            const float* __restrict__ ws,
                                                            float* __restrict__ out) {
    __shared__ short Bs[TJ * LDB];
    __shared__ float red[4];

    const int tid  = threadIdx.x;
    const int lane = tid & 63;
    const int wave = tid >> 6;
    const int quad = lane >> 4;   // 0..3
    const int l16  = lane & 15;   // 0..15

    const int ti = blockIdx.x >> 6;   // 0..31
    const int tj = blockIdx.x & 63;   // 0..63
    const int i0 = ti * TI;
    const int j0 = tj * TJ;

    // ---- Phase 1: stage all_x tile (128 rows x 128 k) -> LDS bf16, Bs[row][k] ----
    {
        const int tcol  = (tid & 31) * 4;   // 0..124, float4 per 32 threads per row
        const int trow0 = tid >> 5;         // 0..7
        #pragma unroll
        for (int r = 0; r < 16; ++r) {
            const int row = r * 8 + trow0;
            const float4 v = *(const float4*)(all_x + (size_t)(j0 + row) * D + tcol);
            short4 b;
            b.x = f2bf(v.x); b.y = f2bf(v.y); b.z = f2bf(v.z); b.w = f2bf(v.w);
            *(short4*)(&Bs[row * LDB + tcol]) = b;
        }
    }

    // ---- Phase 2: A fragments (sub_x) direct from global, fp32 -> bf16 ----
    // A-layout (16x16x32, guide-verified): lane holds A[m = lane&15][k = quad*8 + j], j=0..7
    short8_t a_frag[2][4];
    #pragma unroll
    for (int s = 0; s < 2; ++s) {
        const int m = i0 + (wave * 2 + s) * 16 + l16;
        const float* ap = sub_x + (size_t)m * D + quad * 8;
        #pragma unroll
        for (int t = 0; t < 4; ++t) {   // kstep: k = t*32 + quad*8
            float4 v0 = *(const float4*)(ap + t * 32);
            float4 v1 = *(const float4*)(ap + t * 32 + 4);
            short8_t f;
            f[0] = f2bf(v0.x); f[1] = f2bf(v0.y); f[2] = f2bf(v0.z); f[3] = f2bf(v0.w);
            f[4] = f2bf(v1.x); f[5] = f2bf(v1.y); f[6] = f2bf(v1.z); f[7] = f2bf(v1.w);
            a_frag[s][t] = f;
        }
    }

    __syncthreads();

    // ---- Phase 3: MFMA. P(tile) = SX * AX^T. B[k][n] = all_x[j0+n][k]. ----
    f32x4 acc[2][8];
    #pragma unroll
    for (int s = 0; s < 2; ++s)
        #pragma unroll
        for (int j = 0; j < 8; ++j)
            acc[s][j] = (f32x4){0.f, 0.f, 0.f, 0.f};

    #pragma unroll
    for (int t = 0; t < 4; ++t) {
        short8_t b_frag[8];
        #pragma unroll
        for (int j = 0; j < 8; ++j)  // B frag: lane holds B[k=quad*8+jj][n=lane&15]
            b_frag[j] = *(const short8_t*)(&Bs[(j * 16 + l16) * LDB + t * 32 + quad * 8]);
        #pragma unroll
        for (int s = 0; s < 2; ++s)
            #pragma unroll
            for (int j = 0; j < 8; ++j)
                acc[s][j] = __builtin_amdgcn_mfma_f32_16x16x32_bf16(a_frag[s][t], b_frag[j],
                                                                    acc[s][j], 0, 0, 0);
    }

    // ---- Phase 4: combine with G (fp32, exact) in MFMA C-layout order ----
    // C/D layout (verified): elem r of lane -> row = quad*4 + r, col = lane&15
    const float* sxn = ws;        // [M]
    const float* axn = ws + M;    // [N]

    float sx[2][4];
    #pragma unroll
    for (int s = 0; s < 2; ++s)
        #pragma unroll
        for (int r = 0; r < 4; ++r)
            sx[s][r] = sxn[i0 + (wave * 2 + s) * 16 + quad * 4 + r];
    float ax[8];
    #pragma unroll
    for (int j = 0; j < 8; ++j)
        ax[j] = axn[j0 + j * 16 + l16];

    float local = 0.0f;
    #pragma unroll
    for (int s = 0; s < 2; ++s) {
        #pragma unroll
        for (int r = 0; r < 4; ++r) {
            const int row = i0 + (wave * 2 + s) * 16 + quad * 4 + r;
            const float* gp = G + (size_t)row * N + j0 + l16;
            const float sv = sx[s][r];
            #pragma unroll
            for (int j = 0; j < 8; ++j) {      // imm offsets 0..448*4B; consecutive 64B halves share lines
                const float g = gp[j * 16];
                local += g * (sv + ax[j] - 2.0f * acc[s][j][r]);
            }
        }
    }

    // ---- Reduce: wave shuffle -> LDS -> one atomic per block (pre-scaled; /2^25 exact) ----
    #pragma unroll
    for (int off = 32; off > 0; off >>= 1) local += __shfl_down(local, off, 64);
    if (lane == 0) red[wave] = local;
    __syncthreads();
    if (tid == 0) {
        const float bsum = red[0] + red[1] + red[2] + red[3];
        atomicAdd(out, bsum * (1.0f / 33554432.0f));   // / (m*n) = / 2^25
    }
}

extern "C" void kernel_launch(void* const* d_in, const int* in_sizes, int n_in,
                              void* d_out, int out_size, void* d_ws, size_t ws_size,
                              hipStream_t stream) {
    const float* G      = (const float*)d_in[0];  // [M,N]
    const float* sub_x  = (const float*)d_in[1];  // [M,D]
    const float* all_x  = (const float*)d_in[2];  // [N,D]
    float* out = (float*)d_out;
    float* ws  = (float*)d_ws;                    // sxn[M] | axn[N]  (48 KB)

    norms_kernel<<<(M + N) / 4, 256, 0, stream>>>(sub_x, all_x, ws, out);  // 3072 blocks (R1 bug: /64)
    graph_loss_kernel<<<(M / TI) * (N / TJ), 256, 0, stream>>>(G, sub_x, all_x, ws, out);
}